// Round 13
// baseline (29865.494 us; speedup 1.0000x reference)
//
#include <hip/hip_runtime.h>
#include <math.h>
#include <stdint.h>

#define SEQ   4096
#define NWG   256
#define NTHR  384
#define FINTAG 0x40000000u

// ws layout in dwords. Cells are 8B {f32 h, u32 tag}.
#define WS_BIG  0                    // big ring  [4][1536] cells
#define WS_SML  12288                // small ring [4][768] cells
#define WS_FIN  18432                // final cells [256]
#define WS_OUTP 18944                // outp [4096][256] f32
#define WS_ZERO WS_OUTP

typedef float f32x4 __attribute__((ext_vector_type(4)));
typedef float f32x2 __attribute__((ext_vector_type(2)));

// fast, saturation-safe activations (v_exp_f32 / v_rcp_f32) — validated R9/R12 (absmax 0.0)
__device__ __forceinline__ float sigf(float x){
  float e = __builtin_amdgcn_exp2f(-1.44269504089f * x);   // exp(-x)
  return __builtin_amdgcn_rcpf(1.0f + e);
}
__device__ __forceinline__ float tanhf_fast(float x){
  float e = __builtin_amdgcn_exp2f(2.88539008178f * x);    // exp(2x)
  return 1.0f - 2.0f * __builtin_amdgcn_rcpf(e + 1.0f);    // +-inf-safe
}

// full 64-lane butterfly: result broadcast to ALL lanes
__device__ __forceinline__ float wsum64(float v){
#pragma unroll
  for (int m = 32; m > 0; m >>= 1) v += __shfl_xor(v, m);
  return v;
}

__device__ __forceinline__ float g_load(const float* p){
  return __hip_atomic_load(p, __ATOMIC_RELAXED, __HIP_MEMORY_SCOPE_AGENT);
}
__device__ __forceinline__ void g_store(float* p, float v){
  __hip_atomic_store(p, v, __ATOMIC_RELAXED, __HIP_MEMORY_SCOPE_AGENT);
}
// single 8B atomic store: {h, tag} — data IS the signal (sc1 -> LLC)
__device__ __forceinline__ void cell_store(float* cell, float h, unsigned tag){
  unsigned long long pk = ((unsigned long long)tag << 32) | (unsigned long long)__float_as_uint(h);
  __hip_atomic_store((unsigned long long*)cell, pk, __ATOMIC_RELAXED, __HIP_MEMORY_SCOPE_AGENT);
}

#define DOT4(acc, wv4, hv4) \
  acc += (wv4)[0]*(hv4)[0] + (wv4)[1]*(hv4)[1] + (wv4)[2]*(hv4)[2] + (wv4)[3]*(hv4)[3];

// R8-proven transport: sc1 (LLC-direct) loads of this wave's DISJOINT slice.
// Big slice: 256 cells/wave -> per lane two dwordx4 (cells 2l,2l+1 and 128+2l,128+2l+1).
#define RETRY_BIG2(bbp, tgv)                                                 \
  for(;;){                                                                   \
    asm volatile(                                                            \
      "global_load_dwordx4 %0, %2, off sc0 sc1\n\t"                          \
      "global_load_dwordx4 %1, %2, off offset:1024 sc0 sc1\n\t"              \
      "s_waitcnt vmcnt(0)"                                                   \
      : "=&v"(B0), "=&v"(B1)                                                 \
      : "v"(bbp) : "memory");                                                \
    unsigned tgu = (unsigned)(tgv);                                          \
    bool ok = (__float_as_uint(B0[1])==tgu) & (__float_as_uint(B0[3])==tgu)  \
            & (__float_as_uint(B1[1])==tgu) & (__float_as_uint(B1[3])==tgu); \
    if (__all(ok)) break;                                                    \
    __builtin_amdgcn_s_sleep(1);                                             \
  }

// Small slice: 128 cells/wave -> one dwordx4 per lane.
#define RETRY_SML1(sbp, tgv)                                                 \
  for(;;){                                                                   \
    asm volatile(                                                            \
      "global_load_dwordx4 %0, %1, off sc0 sc1\n\t"                          \
      "s_waitcnt vmcnt(0)"                                                   \
      : "=&v"(S0)                                                            \
      : "v"(sbp) : "memory");                                                \
    unsigned tgu = (unsigned)(tgv);                                          \
    bool ok = (__float_as_uint(S0[1])==tgu) & (__float_as_uint(S0[3])==tgu); \
    if (__all(ok)) break;                                                    \
    __builtin_amdgcn_s_sleep(1);                                             \
  }

__global__ void init_ws(float* ws){
  int i = threadIdx.x + blockIdx.x*blockDim.x;
  for (; i < WS_ZERO; i += blockDim.x*gridDim.x)
    __hip_atomic_store(ws + i, 0.0f, __ATOMIC_RELAXED, __HIP_MEMORY_SCOPE_AGENT);
}

__global__ __launch_bounds__(NTHR, 1) void lstm_ae(
    const float* __restrict__ x,
    const float* __restrict__ e1Wih, const float* __restrict__ e1Whh,
    const float* __restrict__ e1bih, const float* __restrict__ e1bhh,
    const float* __restrict__ e2Wih, const float* __restrict__ e2Whh,
    const float* __restrict__ e2bih, const float* __restrict__ e2bhh,
    const float* __restrict__ d1Wih, const float* __restrict__ d1Whh,
    const float* __restrict__ d1bih, const float* __restrict__ d1bhh,
    const float* __restrict__ d2Wih, const float* __restrict__ d2Whh,
    const float* __restrict__ d2bih, const float* __restrict__ d2bhh,
    const float* __restrict__ outW, const float* __restrict__ outb,
    float* __restrict__ out, float* __restrict__ ws)
{
  const int w    = blockIdx.x;
  const int tid  = threadIdx.x;
  const int lane = tid & 63;
  const int v    = tid >> 6;          // wave 0..5 == unit index (unit-parallel)

  float* outp = ws + WS_OUTP;

  __shared__ float lx[SEQ];           // 16 KB input
  __shared__ float lhB[2][1536];      // staged big h, double-buffered
  __shared__ float lhS[2][768];       // staged small h, double-buffered
  __shared__ float lgS[12];           // small gate pre-acts, idx = k*3+su
  __shared__ float lops[6];           // out partials per big unit

  for (int i = tid; i < SEQ; i += NTHR) lx[i] = x[i];

  // ---- EN weights, unit-parallel: wave v owns big unit 6w+v (4 gate rows) ----
  // frag (q,j) multiplies h[256q + 4*lane + j].
  f32x4 wR[4][6];    // e1Whh rows k*1536+6w+v (K=1536)  -> reused for d2Whh
  float wihB[4], biasB[4];
#pragma unroll
  for (int k = 0; k < 4; ++k){
    const int row = k*1536 + 6*w + v;
    const float* p = e1Whh + (size_t)row*1536 + 4*lane;
#pragma unroll
    for (int q = 0; q < 6; ++q) wR[k][q] = *(const f32x4*)(p + 256*q);
    wihB[k]  = e1Wih[row];
    biasB[k] = e1bih[row] + e1bhh[row];
  }
  // e2: 12 rows (gate k, small-unit su), idx=k*3+su; wave v owns idx 2v, 2v+1
  f32x4 wA[2][6], wB2[2][3];
  float biasS[2];
#pragma unroll
  for (int j = 0; j < 2; ++j){
    const int idx = 2*v + j;
    const int row = (idx/3)*768 + 3*w + (idx%3);
    const float* pi = e2Wih + (size_t)row*1536 + 4*lane;
#pragma unroll
    for (int q = 0; q < 6; ++q) wA[j][q] = *(const f32x4*)(pi + 256*q);
    const float* ph = e2Whh + (size_t)row*768 + 4*lane;
#pragma unroll
    for (int q = 0; q < 3; ++q) wB2[j][q] = *(const f32x4*)(ph + 256*q);
    biasS[j] = e2bih[row] + e2bhh[row];
  }

  float cB = 0.0f;   // big cell state: broadcast in wave v (unit 6w+v)
  float cS = 0.0f;   // small cell state: EN = wave0 lanes 0-2; D = waves 0-2 broadcast
  const float ob = outb[0];

  __syncthreads();   // lx staged

  // ========== Phase EN: critical = e1 (unit-parallel, in-wave act); e2 deferred ==========
  // packet g: big = h1[g] (tag g), small = h2[g-1] (tag g)
  for (int g = 0; g <= SEQ; ++g){
    const int slot = g & 3, buf = g & 1;
    {  // --- critical: catch big h1[g], 6-way split ---
      const float* bb = ws + WS_BIG + slot*3072 + (256*v + 2*lane)*2;
      f32x4 B0, B1;
      RETRY_BIG2(bb, g);
      *(f32x2*)&lhB[buf][256*v +       2*lane] = f32x2{B0[0], B0[2]};
      *(f32x2*)&lhB[buf][256*v + 128 + 2*lane] = f32x2{B1[0], B1[2]};
    }
    __syncthreads();                   // S1: big staged

    if (g < SEQ){                      // e1: 4 gate rows of unit 6w+v, in-wave
      f32x4 H[6];
#pragma unroll
      for (int q = 0; q < 6; ++q) H[q] = *(const f32x4*)&lhB[buf][256*q + 4*lane];
      float a0=0.f,a1=0.f,a2=0.f,a3=0.f;
#pragma unroll
      for (int q = 0; q < 6; ++q){
        DOT4(a0, wR[0][q], H[q]); DOT4(a1, wR[1][q], H[q]);
        DOT4(a2, wR[2][q], H[q]); DOT4(a3, wR[3][q], H[q]);
      }
      a0=wsum64(a0); a1=wsum64(a1); a2=wsum64(a2); a3=wsum64(a3);
      float xt = lx[g];
      float gi = a0 + wihB[0]*xt + biasB[0];
      float gf = a1 + wihB[1]*xt + biasB[1];
      float gg = a2 + wihB[2]*xt + biasB[2];
      float go = a3 + wihB[3]*xt + biasB[3];
      cB = sigf(gf)*cB + sigf(gi)*tanhf_fast(gg);
      float hv = sigf(go)*tanhf_fast(cB);
      if (lane == 0)                   // store h1[g+1] — NO barrier needed
        cell_store(ws + WS_BIG + ((g+1)&3)*3072 + (6*w+v)*2, hv, (unsigned)(g+1));
    }

    // --- deferred: catch small h2[g-1], e2, store h2[g] ---
    if (g >= 1){
      const float* sb = ws + WS_SML + slot*1536 + (128*v + 2*lane)*2;
      f32x4 S0;
      RETRY_SML1(sb, g);
      *(f32x2*)&lhS[buf][128*v + 2*lane] = f32x2{S0[0], S0[2]};
    }
    __syncthreads();                   // S2: small staged

    if (g >= 1){                       // e2: 2 rows per wave (gate-spread)
      f32x4 H[6], S[3];
#pragma unroll
      for (int q = 0; q < 6; ++q) H[q] = *(const f32x4*)&lhB[buf][256*q + 4*lane];
#pragma unroll
      for (int q = 0; q < 3; ++q) S[q] = *(const f32x4*)&lhS[buf][256*q + 4*lane];
      float b0=0.f, b1=0.f;
#pragma unroll
      for (int q = 0; q < 6; ++q){ DOT4(b0, wA[0][q], H[q]); DOT4(b1, wA[1][q], H[q]); }
#pragma unroll
      for (int q = 0; q < 3; ++q){ DOT4(b0, wB2[0][q], S[q]); DOT4(b1, wB2[1][q], S[q]); }
      b0 = wsum64(b0); b1 = wsum64(b1);
      if (lane == 0){ lgS[2*v] = b0 + biasS[0]; lgS[2*v+1] = b1 + biasS[1]; }
    }
    __syncthreads();                   // S3: lgS ready

    // Store small tag g+1 UNCONDITIONALLY (g==0: zero initial state — R11 lesson)
    if (v == 0 && lane < 3){
      float hv = 0.0f;
      if (g >= 1){
        float gi=lgS[lane], gf=lgS[3+lane], gg=lgS[6+lane], go=lgS[9+lane];
        cS = sigf(gf)*cS + sigf(gi)*tanhf_fast(gg);
        hv = sigf(go)*tanhf_fast(cS);
      }
      cell_store(ws + WS_SML + ((g+1)&3)*1536 + (3*w+lane)*2, hv, (unsigned)(g+1));
    }
  }

  // ========== Phase Z: zw (broadcast in waves 0-2) from small packet SEQ+1 = z ==========
  f32x4 wZ[4][3]; float bz[4];
  if (v < 3){
#pragma unroll
    for (int k = 0; k < 4; ++k){
      const int row = k*768 + 3*w + v;
      const float* p = d1Wih + (size_t)row*768 + 4*lane;
#pragma unroll
      for (int q = 0; q < 3; ++q) wZ[k][q] = *(const f32x4*)(p + 256*q);
      bz[k] = d1bih[row] + d1bhh[row];
    }
  }
  float zw0=0.f, zw1=0.f, zw2=0.f, zw3=0.f;
  {
    const int tg = SEQ+1, slot = tg & 3, buf2 = tg & 1;
    const float* sb = ws + WS_SML + slot*1536 + (128*v + 2*lane)*2;
    f32x4 S0;
    RETRY_SML1(sb, tg);
    *(f32x2*)&lhS[buf2][128*v + 2*lane] = f32x2{S0[0], S0[2]};
    __syncthreads();
    if (v < 3){
      f32x4 S[3];
#pragma unroll
      for (int q = 0; q < 3; ++q) S[q] = *(const f32x4*)&lhS[buf2][256*q + 4*lane];
      float z0=0.f,z1=0.f,z2=0.f,z3=0.f;
#pragma unroll
      for (int q = 0; q < 3; ++q){
        DOT4(z0, wZ[0][q], S[q]); DOT4(z1, wZ[1][q], S[q]);
        DOT4(z2, wZ[2][q], S[q]); DOT4(z3, wZ[3][q], S[q]);
      }
      zw0 = wsum64(z0) + bz[0]; zw1 = wsum64(z1) + bz[1];
      zw2 = wsum64(z2) + bz[2]; zw3 = wsum64(z3) + bz[3];
    }
  }

  // ---- D weights: d2 unit-parallel (wave v = big unit 6w+v); d1 waves 0-2 ----
  f32x4 wA2[4][3];   // d2Wih rows k*1536+6w+v (K=768)
#pragma unroll
  for (int k = 0; k < 4; ++k){
    const int row = k*1536 + 6*w + v;
    const float* p = d2Whh + (size_t)row*1536 + 4*lane;
#pragma unroll
    for (int q = 0; q < 6; ++q) wR[k][q] = *(const f32x4*)(p + 256*q);
    const float* pi = d2Wih + (size_t)row*768 + 4*lane;
#pragma unroll
    for (int q = 0; q < 3; ++q) wA2[k][q] = *(const f32x4*)(pi + 256*q);
    biasB[k] = d2bih[row] + d2bhh[row];
  }
  f32x4 wD1[4][3];   // d1Whh rows k*768+3w+v (waves 0-2)
  if (v < 3){
#pragma unroll
    for (int k = 0; k < 4; ++k){
      const int row = k*768 + 3*w + v;
      const float* p = d1Whh + (size_t)row*768 + 4*lane;
#pragma unroll
      for (int q = 0; q < 3; ++q) wD1[k][q] = *(const f32x4*)(p + 256*q);
    }
  }
  const float ow = outW[6*w + v];
  cB = 0.0f; cS = 0.0f;

  // ========== Phase D: critical = d1 (waves 0-2, in-wave act); d2 deferred ==========
  // packet pc=SEQ+1+t: small = hd1[t], big = hd2[t-1]
  for (int t = 0; t <= SEQ; ++t){
    const int pc = SEQ+1+t, slot = pc & 3, buf = pc & 1;
    if (t >= 1){  // --- critical: catch small hd1[t] ---
      const float* sb = ws + WS_SML + slot*1536 + (128*v + 2*lane)*2;
      f32x4 S0;
      RETRY_SML1(sb, pc);
      *(f32x2*)&lhS[buf][128*v + 2*lane] = f32x2{S0[0], S0[2]};
    }
    __syncthreads();                   // S1: small staged

    if (t < SEQ && v < 3){             // d1: 4 gate rows of small unit 3w+v, in-wave
      f32x4 S[3];
      if (t >= 1){
#pragma unroll
        for (int q = 0; q < 3; ++q) S[q] = *(const f32x4*)&lhS[buf][256*q + 4*lane];
      } else {
#pragma unroll
        for (int q = 0; q < 3; ++q) S[q] = (f32x4)0.0f;
      }
      float d0=0.f,d1v=0.f,d2v=0.f,d3=0.f;
#pragma unroll
      for (int q = 0; q < 3; ++q){
        DOT4(d0, wD1[0][q], S[q]); DOT4(d1v, wD1[1][q], S[q]);
        DOT4(d2v, wD1[2][q], S[q]); DOT4(d3, wD1[3][q], S[q]);
      }
      d0=wsum64(d0); d1v=wsum64(d1v); d2v=wsum64(d2v); d3=wsum64(d3);
      float gi = d0 + zw0, gf = d1v + zw1, gg = d2v + zw2, go = d3 + zw3;
      cS = sigf(gf)*cS + sigf(gi)*tanhf_fast(gg);
      float hv = sigf(go)*tanhf_fast(cS);
      if (lane == 0)                   // store hd1[t+1] — NO barrier needed
        cell_store(ws + WS_SML + ((pc+1)&3)*1536 + (3*w+v)*2, hv, (unsigned)(pc+1));
    }
    if (t == 0 && v == 0 && lane < 6)  // hd2[0] = 0 (slot holds stale data)
      cell_store(ws + WS_BIG + ((pc+1)&3)*3072 + (6*w+lane)*2, 0.0f, (unsigned)(pc+1));

    // --- deferred: catch big hd2[t-1], d2 (unit-parallel), store + out partial ---
    if (t >= 1){
      const float* bb = ws + WS_BIG + slot*3072 + (256*v + 2*lane)*2;
      f32x4 B0, B1;
      RETRY_BIG2(bb, pc);
      *(f32x2*)&lhB[buf][256*v +       2*lane] = f32x2{B0[0], B0[2]};
      *(f32x2*)&lhB[buf][256*v + 128 + 2*lane] = f32x2{B1[0], B1[2]};
    }
    __syncthreads();                   // S2: big staged

    if (t >= 1){                       // d2: 4 gate rows of unit 6w+v, in-wave
      f32x4 H[6], S[3];
#pragma unroll
      for (int q = 0; q < 6; ++q) H[q] = *(const f32x4*)&lhB[buf][256*q + 4*lane];
#pragma unroll
      for (int q = 0; q < 3; ++q) S[q] = *(const f32x4*)&lhS[buf][256*q + 4*lane];
      float a0=0.f,a1=0.f,a2=0.f,a3=0.f;
#pragma unroll
      for (int q = 0; q < 6; ++q){
        DOT4(a0, wR[0][q], H[q]); DOT4(a1, wR[1][q], H[q]);
        DOT4(a2, wR[2][q], H[q]); DOT4(a3, wR[3][q], H[q]);
      }
#pragma unroll
      for (int q = 0; q < 3; ++q){
        DOT4(a0, wA2[0][q], S[q]); DOT4(a1, wA2[1][q], S[q]);
        DOT4(a2, wA2[2][q], S[q]); DOT4(a3, wA2[3][q], S[q]);
      }
      a0=wsum64(a0); a1=wsum64(a1); a2=wsum64(a2); a3=wsum64(a3);
      float gi = a0 + biasB[0], gf = a1 + biasB[1];
      float gg = a2 + biasB[2], go = a3 + biasB[3];
      cB = sigf(gf)*cB + sigf(gi)*tanhf_fast(gg);
      float hv = sigf(go)*tanhf_fast(cB);
      if (lane == 0){
        cell_store(ws + WS_BIG + ((pc+1)&3)*3072 + (6*w+v)*2, hv, (unsigned)(pc+1));
        lops[v] = hv * ow;
      }
    }
    __syncthreads();                   // S3: lops ready
    if (t >= 1 && tid == 0)
      g_store(&outp[(size_t)(t-1)*NWG + w],
              lops[0]+lops[1]+lops[2]+lops[3]+lops[4]+lops[5]);
  }

  // ================= Finalize + reduce =================
  if (v == 0){
    asm volatile("s_waitcnt vmcnt(0)" ::: "memory");   // wave0's outp stores acked
    if (lane == 0) cell_store(ws + WS_FIN + w*2, 0.0f, FINTAG);
    const float* fb = ws + WS_FIN + (4*lane)*2;
    f32x4 F0, F1;
    for(;;){
      asm volatile(
        "global_load_dwordx4 %0, %2, off sc0 sc1\n\t"
        "global_load_dwordx4 %1, %2, off offset:16 sc0 sc1\n\t"
        "s_waitcnt vmcnt(0)"
        : "=&v"(F0), "=&v"(F1) : "v"(fb) : "memory");
      bool ok = (__float_as_uint(F0[1])==FINTAG)&(__float_as_uint(F0[3])==FINTAG)
              & (__float_as_uint(F1[1])==FINTAG)&(__float_as_uint(F1[3])==FINTAG);
      if (__all(ok)) break;
      __builtin_amdgcn_s_sleep(1);
    }
  }
  __syncthreads();
  if (tid < 256){
    const int tau = w*16 + (tid >> 4);
    const int s4  = tid & 15;
    float s = 0.f;
#pragma unroll
    for (int j = 0; j < 16; ++j) s += g_load(&outp[(size_t)tau*NWG + s4 + 16*j]);
    s += __shfl_xor(s,8); s += __shfl_xor(s,4); s += __shfl_xor(s,2); s += __shfl_xor(s,1);
    if (s4 == 0) out[tau] = s + ob;
  }
}

extern "C" void kernel_launch(void* const* d_in, const int* in_sizes, int n_in,
                              void* d_out, int out_size, void* d_ws, size_t ws_size,
                              hipStream_t stream){
  (void)in_sizes; (void)n_in; (void)out_size; (void)ws_size;
  const float* x     = (const float*)d_in[0];
  const float* e1Wih = (const float*)d_in[1];
  const float* e1Whh = (const float*)d_in[2];
  const float* e1bih = (const float*)d_in[3];
  const float* e1bhh = (const float*)d_in[4];
  const float* e2Wih = (const float*)d_in[5];
  const float* e2Whh = (const float*)d_in[6];
  const float* e2bih = (const float*)d_in[7];
  const float* e2bhh = (const float*)d_in[8];
  const float* d1Wih = (const float*)d_in[9];
  const float* d1Whh = (const float*)d_in[10];
  const float* d1bih = (const float*)d_in[11];
  const float* d1bhh = (const float*)d_in[12];
  const float* d2Wih = (const float*)d_in[13];
  const float* d2Whh = (const float*)d_in[14];
  const float* d2bih = (const float*)d_in[15];
  const float* d2bhh = (const float*)d_in[16];
  const float* outW  = (const float*)d_in[17];
  const float* outb  = (const float*)d_in[18];
  float* out = (float*)d_out;
  float* ws  = (float*)d_ws;

  hipLaunchKernelGGL(init_ws, dim3(32), dim3(256), 0, stream, ws);

  // Plain launch (NOT cooperative): co-residency follows from grid == #CUs
  // at 1 block/CU (high-VGPR kernel); cooperative launch rejects this config.
  hipLaunchKernelGGL(lstm_ae, dim3(NWG), dim3(NTHR), 0, stream,
                     x,
                     e1Wih, e1Whh, e1bih, e1bhh,
                     e2Wih, e2Whh, e2bih, e2bhh,
                     d1Wih, d1Whh, d1bih, d1bhh,
                     d2Wih, d2Whh, d2bih, d2bhh,
                     outW,  outb,  out,   ws);
}

// Round 14
// 28113.882 us; speedup vs baseline: 1.0623x; 1.0623x over previous
//
#include <hip/hip_runtime.h>
#include <math.h>
#include <stdint.h>

#define SEQ   4096
#define NWG   256
#define NTHR  256
#define FINTAG 0x40000000u

// ws layout in dwords. Cells are 8B {f32 h, u32 tag}.
#define WS_BIG  0                    // big ring  [4][1536] cells
#define WS_SML  12288                // small ring [4][768] cells
#define WS_FIN  18432                // final cells [256]
#define WS_OUTP 18944                // outp [4096][256] f32
#define WS_ZERO WS_OUTP

typedef float f32x4 __attribute__((ext_vector_type(4)));
typedef float f32x2 __attribute__((ext_vector_type(2)));

// fast, saturation-safe activations (v_exp_f32 / v_rcp_f32) — validated R9/R12
__device__ __forceinline__ float sigf(float x){
  float e = __builtin_amdgcn_exp2f(-1.44269504089f * x);   // exp(-x)
  return __builtin_amdgcn_rcpf(1.0f + e);
}
__device__ __forceinline__ float tanhf_fast(float x){
  float e = __builtin_amdgcn_exp2f(2.88539008178f * x);    // exp(2x)
  return 1.0f - 2.0f * __builtin_amdgcn_rcpf(e + 1.0f);    // +-inf-safe
}

__device__ __forceinline__ float wsum64(float v){
#pragma unroll
  for (int m = 32; m > 0; m >>= 1) v += __shfl_xor(v, m);
  return v;
}

__device__ __forceinline__ float g_load(const float* p){
  return __hip_atomic_load(p, __ATOMIC_RELAXED, __HIP_MEMORY_SCOPE_AGENT);
}
__device__ __forceinline__ void g_store(float* p, float v){
  __hip_atomic_store(p, v, __ATOMIC_RELAXED, __HIP_MEMORY_SCOPE_AGENT);
}
// single 8B atomic store: {h, tag} — data IS the signal (sc1 -> LLC)
__device__ __forceinline__ void cell_store(float* cell, float h, unsigned tag){
  unsigned long long pk = ((unsigned long long)tag << 32) | (unsigned long long)__float_as_uint(h);
  __hip_atomic_store((unsigned long long*)cell, pk, __ATOMIC_RELAXED, __HIP_MEMORY_SCOPE_AGENT);
}

#define DOT4(acc, wv4, hv4) \
  acc += (wv4)[0]*(hv4)[0] + (wv4)[1]*(hv4)[1] + (wv4)[2]*(hv4)[2] + (wv4)[3]*(hv4)[3];

#define BIG_OK(tgu) \
  ((__float_as_uint(B0[1])==(tgu)) & (__float_as_uint(B0[3])==(tgu)) \
 & (__float_as_uint(B1[1])==(tgu)) & (__float_as_uint(B1[3])==(tgu)) \
 & (__float_as_uint(B2[1])==(tgu)) & (__float_as_uint(B2[3])==(tgu)))
#define SML_OK(tgu) \
  ((__float_as_uint(S0[1])==(tgu)) & (__float_as_uint(S0[3])==(tgu)) \
 & (__float_as_uint(S1v[1])==(tgu)))

// ---- pipelined catch: ISSUE (no wait) ... later CHECK (wait + verify + retry) ----
#define ISSUE_BIG(bbp)                                                       \
  asm volatile(                                                              \
    "global_load_dwordx4 %0, %3, off sc0 sc1\n\t"                            \
    "global_load_dwordx4 %1, %3, off offset:1024 sc0 sc1\n\t"                \
    "global_load_dwordx4 %2, %3, off offset:2048 sc0 sc1"                    \
    : "=&v"(B0), "=&v"(B1), "=&v"(B2) : "v"(bbp) : "memory");

#define CHECK_BIG(bbp, tgv) {                                                \
    asm volatile("s_waitcnt vmcnt(0)"                                        \
      : "+v"(B0), "+v"(B1), "+v"(B2) :: "memory");                           \
    const unsigned tgu_ = (unsigned)(tgv);                                   \
    bool ok_ = BIG_OK(tgu_);                                                 \
    while (!__all(ok_)){                                                     \
      __builtin_amdgcn_s_sleep(1);                                           \
      asm volatile(                                                          \
        "global_load_dwordx4 %0, %3, off sc0 sc1\n\t"                        \
        "global_load_dwordx4 %1, %3, off offset:1024 sc0 sc1\n\t"            \
        "global_load_dwordx4 %2, %3, off offset:2048 sc0 sc1\n\t"            \
        "s_waitcnt vmcnt(0)"                                                 \
        : "=&v"(B0), "=&v"(B1), "=&v"(B2) : "v"(bbp) : "memory");            \
      ok_ = BIG_OK(tgu_);                                                    \
    } }

#define ISSUE_SML(sbp, sb2p)                                                 \
  asm volatile(                                                              \
    "global_load_dwordx4 %0, %2, off sc0 sc1\n\t"                            \
    "global_load_dwordx2 %1, %3, off sc0 sc1"                                \
    : "=&v"(S0), "=&v"(S1v) : "v"(sbp), "v"(sb2p) : "memory");

#define CHECK_SML(sbp, sb2p, tgv) {                                          \
    asm volatile("s_waitcnt vmcnt(0)"                                        \
      : "+v"(S0), "+v"(S1v) :: "memory");                                    \
    const unsigned tgu_ = (unsigned)(tgv);                                   \
    bool ok_ = SML_OK(tgu_);                                                 \
    while (!__all(ok_)){                                                     \
      __builtin_amdgcn_s_sleep(1);                                           \
      asm volatile(                                                          \
        "global_load_dwordx4 %0, %2, off sc0 sc1\n\t"                        \
        "global_load_dwordx2 %1, %3, off sc0 sc1\n\t"                        \
        "s_waitcnt vmcnt(0)"                                                 \
        : "=&v"(S0), "=&v"(S1v) : "v"(sbp), "v"(sb2p) : "memory");           \
      ok_ = SML_OK(tgu_);                                                    \
    } }

// plain retries (mid-iteration, operand already ~0.5µs old)
#define RETRY_BIG(bbp, tgv)  { ISSUE_BIG(bbp)  CHECK_BIG(bbp, tgv) }
#define RETRY_SML(sbp, sb2p, tgv) { ISSUE_SML(sbp, sb2p) CHECK_SML(sbp, sb2p, tgv) }

__global__ void init_ws(float* ws){
  int i = threadIdx.x + blockIdx.x*blockDim.x;
  for (; i < WS_ZERO; i += blockDim.x*gridDim.x)
    __hip_atomic_store(ws + i, 0.0f, __ATOMIC_RELAXED, __HIP_MEMORY_SCOPE_AGENT);
}

__global__ __launch_bounds__(NTHR, 1) void lstm_ae(
    const float* __restrict__ x,
    const float* __restrict__ e1Wih, const float* __restrict__ e1Whh,
    const float* __restrict__ e1bih, const float* __restrict__ e1bhh,
    const float* __restrict__ e2Wih, const float* __restrict__ e2Whh,
    const float* __restrict__ e2bih, const float* __restrict__ e2bhh,
    const float* __restrict__ d1Wih, const float* __restrict__ d1Whh,
    const float* __restrict__ d1bih, const float* __restrict__ d1bhh,
    const float* __restrict__ d2Wih, const float* __restrict__ d2Whh,
    const float* __restrict__ d2bih, const float* __restrict__ d2bhh,
    const float* __restrict__ outW, const float* __restrict__ outb,
    float* __restrict__ out, float* __restrict__ ws)
{
  const int w    = blockIdx.x;
  const int tid  = threadIdx.x;
  const int lane = tid & 63;
  const int v    = tid >> 6;          // wave 0..3 == gate index

  float* outp = ws + WS_OUTP;

  __shared__ float lx[SEQ];           // 16 KB input
  __shared__ float lhB[2][1536];      // staged big h, double-buffered
  __shared__ float lhS[2][768];       // staged small h, double-buffered
  __shared__ float lgB[24], lgS[12];  // gate pre-activations [gate][unit]

  f32x4 B0, B1, B2, S0;               // pipelined catch registers
  f32x2 S1v;

  for (int i = tid; i < SEQ; i += NTHR) lx[i] = x[i];

  // ---- weights: gate-parallel mapping (R12). wave v owns gate v of all units.
  f32x4 wR[6][6];   // e1Whh -> d2Whh      (K=1536)
  f32x4 wA[18];     // e2Wih r*6+q (r<3) -> d2Wih r*3+q (r<6)
  f32x4 wB[9];      // e2Whh r*3+q -> d1Wih (Z) -> d1Whh (D)
  float wihB[6], biasB[6], biasS[3], zw[3], bz[3];

#pragma unroll
  for (int r = 0; r < 6; ++r){
    const int row = v*1536 + 6*w + r;
    const float* p = e1Whh + (size_t)row*1536 + 4*lane;
#pragma unroll
    for (int q = 0; q < 6; ++q) wR[r][q] = *(const f32x4*)(p + 256*q);
    wihB[r]  = e1Wih[row];
    biasB[r] = e1bih[row] + e1bhh[row];
  }
#pragma unroll
  for (int r = 0; r < 3; ++r){
    const int row = v*768 + 3*w + r;
    const float* pi = e2Wih + (size_t)row*1536 + 4*lane;
#pragma unroll
    for (int q = 0; q < 6; ++q) wA[r*6+q] = *(const f32x4*)(pi + 256*q);
    const float* ph = e2Whh + (size_t)row*768 + 4*lane;
#pragma unroll
    for (int q = 0; q < 3; ++q) wB[r*3+q] = *(const f32x4*)(ph + 256*q);
    biasS[r] = e2bih[row] + e2bhh[row];
  }

  float cB = 0.0f, cS = 0.0f;   // wave0 lanes 0-5: big cell; lanes 8-10: small
  const float ob = outb[0];
  float ow = (v == 0 && lane < 6) ? outW[6*w + lane] : 0.0f;

  __syncthreads();   // lx staged

  // prologue: issue big packet 0 (zeroed ws: tag 0 matches immediately)
  {
    const float* bb = ws + WS_BIG + 0*3072 + (384*v + 2*lane)*2;
    ISSUE_BIG(bb)
  }

  // ========== Phase EN: critical = e1 big chain; e2 deferred ==========
  // packet g: big = h1[g] (tag g), small = h2[g-1] (tag g)
  for (int g = 0; g <= SEQ; ++g){
    const int slot = g & 3, buf = g & 1;
    {  // --- top: check big h1[g] (loads issued last iteration) ---
      const float* bb = ws + WS_BIG + slot*3072 + (384*v + 2*lane)*2;
      CHECK_BIG(bb, g)
      *(f32x2*)&lhB[buf][384*v +       2*lane] = f32x2{B0[0], B0[2]};
      *(f32x2*)&lhB[buf][384*v + 128 + 2*lane] = f32x2{B1[0], B1[2]};
      *(f32x2*)&lhB[buf][384*v + 256 + 2*lane] = f32x2{B2[0], B2[2]};
    }
    __syncthreads();                   // S1: big staged

    if (g < SEQ){                      // e1: gate v of units 0..5
      f32x4 H[6];
#pragma unroll
      for (int q = 0; q < 6; ++q) H[q] = *(const f32x4*)&lhB[buf][256*q + 4*lane];
      float a0=0.f,a1=0.f,a2=0.f,a3=0.f,a4=0.f,a5=0.f;
#pragma unroll
      for (int q = 0; q < 6; ++q){
        DOT4(a0, wR[0][q], H[q]); DOT4(a1, wR[1][q], H[q]); DOT4(a2, wR[2][q], H[q]);
        DOT4(a3, wR[3][q], H[q]); DOT4(a4, wR[4][q], H[q]); DOT4(a5, wR[5][q], H[q]);
      }
      a0=wsum64(a0); a1=wsum64(a1); a2=wsum64(a2);
      a3=wsum64(a3); a4=wsum64(a4); a5=wsum64(a5);
      if (lane == 0){
        float xt = lx[g];
        lgB[v*6+0]=a0+wihB[0]*xt+biasB[0]; lgB[v*6+1]=a1+wihB[1]*xt+biasB[1];
        lgB[v*6+2]=a2+wihB[2]*xt+biasB[2]; lgB[v*6+3]=a3+wihB[3]*xt+biasB[3];
        lgB[v*6+4]=a4+wihB[4]*xt+biasB[4]; lgB[v*6+5]=a5+wihB[5]*xt+biasB[5];
      }
    }
    __syncthreads();                   // S2: lgB ready

    if (v == 0 && g < SEQ && lane < 6){  // store h1[g+1] ASAP — recurrence-critical
      float gi=lgB[lane],gf=lgB[6+lane],gg=lgB[12+lane],go=lgB[18+lane];
      cB = sigf(gf)*cB + sigf(gi)*tanhf_fast(gg);
      cell_store(ws + WS_BIG + ((g+1)&3)*3072 + (6*w+lane)*2,
                 sigf(go)*tanhf_fast(cB), (unsigned)(g+1));
    }

    // --- deferred: catch small h2[g-1] (plain retry; data ~1 iter old) ---
    if (g >= 1){
      const float* smlb = ws + WS_SML + slot*1536;
      const float* sb  = smlb + (192*v + 2*lane)*2;
      const float* sb2 = smlb + (192*v + 128 + lane)*2;
      RETRY_SML(sb, sb2, g)
      *(f32x2*)&lhS[buf][192*v + 2*lane] = f32x2{S0[0], S0[2]};
      lhS[buf][192*v + 128 + lane] = S1v[0];
    }
    if (g < SEQ){                      // pipeline: issue big for packet g+1 now;
      const float* bbn = ws + WS_BIG + ((g+1)&3)*3072 + (384*v + 2*lane)*2;
      ISSUE_BIG(bbn)                   // e2 segment + barriers cover the latency
    }
    __syncthreads();                   // S3: small staged

    if (g >= 1){                       // e2: gate v of units 0..2
      f32x4 H[6], S[3];
#pragma unroll
      for (int q = 0; q < 6; ++q) H[q] = *(const f32x4*)&lhB[buf][256*q + 4*lane];
#pragma unroll
      for (int q = 0; q < 3; ++q) S[q] = *(const f32x4*)&lhS[buf][256*q + 4*lane];
      float b0=0.f,b1=0.f,b2=0.f;
#pragma unroll
      for (int q = 0; q < 6; ++q){
        DOT4(b0, wA[0*6+q], H[q]); DOT4(b1, wA[1*6+q], H[q]); DOT4(b2, wA[2*6+q], H[q]);
      }
#pragma unroll
      for (int q = 0; q < 3; ++q){
        DOT4(b0, wB[0*3+q], S[q]); DOT4(b1, wB[1*3+q], S[q]); DOT4(b2, wB[2*3+q], S[q]);
      }
      b0=wsum64(b0); b1=wsum64(b1); b2=wsum64(b2);
      if (lane == 0){
        lgS[v*3+0]=b0+biasS[0]; lgS[v*3+1]=b1+biasS[1]; lgS[v*3+2]=b2+biasS[2];
      }
    }
    __syncthreads();                   // S4: lgS ready

    // Store small tag g+1 UNCONDITIONALLY (g==0: zero initial state — R11 lesson)
    if (v == 0 && lane >= 8 && lane < 11){
      int u = lane - 8;
      float hv = 0.0f;
      if (g >= 1){
        float gi=lgS[u],gf=lgS[3+u],gg=lgS[6+u],go=lgS[9+u];
        cS = sigf(gf)*cS + sigf(gi)*tanhf_fast(gg);
        hv = sigf(go)*tanhf_fast(cS);
      }
      cell_store(ws + WS_SML + ((g+1)&3)*1536 + (3*w+u)*2, hv, (unsigned)(g+1));
    }
  }

  // ========== Phase Z: zW = d1_Wih @ z + bias (packet SEQ+1 small = z) ==========
  {
#pragma unroll
    for (int r = 0; r < 3; ++r){
      const int row = v*768 + 3*w + r;
      const float* p = d1Wih + (size_t)row*768 + 4*lane;
#pragma unroll
      for (int q = 0; q < 3; ++q) wB[r*3+q] = *(const f32x4*)(p + 256*q);
      bz[r] = d1bih[row] + d1bhh[row];
    }
    const int tg = SEQ+1, slot = tg & 3, buf = tg & 1;
    const float* smlb = ws + WS_SML + slot*1536;
    const float* sb  = smlb + (192*v + 2*lane)*2;
    const float* sb2 = smlb + (192*v + 128 + lane)*2;
    RETRY_SML(sb, sb2, tg)
    *(f32x2*)&lhS[buf][192*v + 2*lane] = f32x2{S0[0], S0[2]};
    lhS[buf][192*v + 128 + lane] = S1v[0];
    __syncthreads();
    f32x4 S[3];
#pragma unroll
    for (int q = 0; q < 3; ++q) S[q] = *(const f32x4*)&lhS[buf][256*q + 4*lane];
    float z0=0.f,z1=0.f,z2=0.f;
#pragma unroll
    for (int q = 0; q < 3; ++q){
      DOT4(z0, wB[0*3+q], S[q]); DOT4(z1, wB[1*3+q], S[q]); DOT4(z2, wB[2*3+q], S[q]);
    }
    zw[0]=wsum64(z0)+bz[0]; zw[1]=wsum64(z1)+bz[1]; zw[2]=wsum64(z2)+bz[2];
  }

  // ---- D-phase weights ----
#pragma unroll
  for (int r = 0; r < 6; ++r){
    const int row = v*1536 + 6*w + r;
    const float* p = d2Whh + (size_t)row*1536 + 4*lane;
#pragma unroll
    for (int q = 0; q < 6; ++q) wR[r][q] = *(const f32x4*)(p + 256*q);
    const float* pi = d2Wih + (size_t)row*768 + 4*lane;
#pragma unroll
    for (int q = 0; q < 3; ++q) wA[r*3+q] = *(const f32x4*)(pi + 256*q);
    biasB[r] = d2bih[row] + d2bhh[row];
  }
#pragma unroll
  for (int r = 0; r < 3; ++r){
    const int row = v*768 + 3*w + r;
    const float* p = d1Whh + (size_t)row*768 + 4*lane;
#pragma unroll
    for (int q = 0; q < 3; ++q) wB[r*3+q] = *(const f32x4*)(p + 256*q);
  }
  cB = 0.0f; cS = 0.0f;

  // ========== Phase D: critical = d1 small chain; d2 deferred ==========
  // packet pc=SEQ+1+t: small = hd1[t], big = hd2[t-1]
  for (int t = 0; t <= SEQ; ++t){
    const int pc = SEQ+1+t, slot = pc & 3, buf = pc & 1;
    if (t >= 1){  // --- top: check small hd1[t] (issued last iteration) ---
      const float* smlb = ws + WS_SML + slot*1536;
      const float* sb  = smlb + (192*v + 2*lane)*2;
      const float* sb2 = smlb + (192*v + 128 + lane)*2;
      CHECK_SML(sb, sb2, pc)
      *(f32x2*)&lhS[buf][192*v + 2*lane] = f32x2{S0[0], S0[2]};
      lhS[buf][192*v + 128 + lane] = S1v[0];
    }
    __syncthreads();                   // S1: small staged

    if (t < SEQ){                      // d1: gate v of units 0..2
      f32x4 S[3];
      if (t >= 1){
#pragma unroll
        for (int q = 0; q < 3; ++q) S[q] = *(const f32x4*)&lhS[buf][256*q + 4*lane];
      } else {
#pragma unroll
        for (int q = 0; q < 3; ++q) S[q] = (f32x4)0.0f;
      }
      float b0=0.f,b1=0.f,b2=0.f;
#pragma unroll
      for (int q = 0; q < 3; ++q){
        DOT4(b0, wB[0*3+q], S[q]); DOT4(b1, wB[1*3+q], S[q]); DOT4(b2, wB[2*3+q], S[q]);
      }
      b0=wsum64(b0); b1=wsum64(b1); b2=wsum64(b2);
      if (lane == 0){
        lgS[v*3+0]=b0+zw[0]; lgS[v*3+1]=b1+zw[1]; lgS[v*3+2]=b2+zw[2];
      }
    }
    __syncthreads();                   // S2: lgS ready

    if (v == 0){                       // store hd1[t+1] ASAP — recurrence-critical
      if (t < SEQ && lane >= 8 && lane < 11){
        int u = lane - 8;
        float gi=lgS[u],gf=lgS[3+u],gg=lgS[6+u],go=lgS[9+u];
        cS = sigf(gf)*cS + sigf(gi)*tanhf_fast(gg);
        cell_store(ws + WS_SML + ((pc+1)&3)*1536 + (3*w+u)*2,
                   sigf(go)*tanhf_fast(cS), (unsigned)(pc+1));
      }
      if (t == 0 && lane < 6)          // hd2[0] = 0 (slot holds stale data)
        cell_store(ws + WS_BIG + ((pc+1)&3)*3072 + (6*w+lane)*2, 0.0f, (unsigned)(pc+1));
    }

    // --- deferred: catch big hd2[t-1] (plain retry; stored end of prev iter) ---
    if (t >= 1){
      const float* bb = ws + WS_BIG + slot*3072 + (384*v + 2*lane)*2;
      RETRY_BIG(bb, pc)
      *(f32x2*)&lhB[buf][384*v +       2*lane] = f32x2{B0[0], B0[2]};
      *(f32x2*)&lhB[buf][384*v + 128 + 2*lane] = f32x2{B1[0], B1[2]};
      *(f32x2*)&lhB[buf][384*v + 256 + 2*lane] = f32x2{B2[0], B2[2]};
    }
    if (t < SEQ){                      // pipeline: issue small for packet pc+1 now
      const float* smlbn = ws + WS_SML + ((pc+1)&3)*1536;
      const float* sbn  = smlbn + (192*v + 2*lane)*2;
      const float* sb2n = smlbn + (192*v + 128 + lane)*2;
      ISSUE_SML(sbn, sb2n)             // d2 segment + barriers cover the latency
    }
    __syncthreads();                   // S3: big staged

    if (t >= 1){                       // d2: big recurrent (H) + small input (S)
      f32x4 H[6], S[3];
#pragma unroll
      for (int q = 0; q < 6; ++q) H[q] = *(const f32x4*)&lhB[buf][256*q + 4*lane];
#pragma unroll
      for (int q = 0; q < 3; ++q) S[q] = *(const f32x4*)&lhS[buf][256*q + 4*lane];
      float a0=0.f,a1=0.f,a2=0.f,a3=0.f,a4=0.f,a5=0.f;
#pragma unroll
      for (int q = 0; q < 6; ++q){
        DOT4(a0, wR[0][q], H[q]); DOT4(a1, wR[1][q], H[q]); DOT4(a2, wR[2][q], H[q]);
        DOT4(a3, wR[3][q], H[q]); DOT4(a4, wR[4][q], H[q]); DOT4(a5, wR[5][q], H[q]);
      }
#pragma unroll
      for (int q = 0; q < 3; ++q){
        DOT4(a0, wA[0*3+q], S[q]); DOT4(a1, wA[1*3+q], S[q]); DOT4(a2, wA[2*3+q], S[q]);
        DOT4(a3, wA[3*3+q], S[q]); DOT4(a4, wA[4*3+q], S[q]); DOT4(a5, wA[5*3+q], S[q]);
      }
      a0=wsum64(a0); a1=wsum64(a1); a2=wsum64(a2);
      a3=wsum64(a3); a4=wsum64(a4); a5=wsum64(a5);
      if (lane == 0){
        lgB[v*6+0]=a0+biasB[0]; lgB[v*6+1]=a1+biasB[1]; lgB[v*6+2]=a2+biasB[2];
        lgB[v*6+3]=a3+biasB[3]; lgB[v*6+4]=a4+biasB[4]; lgB[v*6+5]=a5+biasB[5];
      }
    }
    __syncthreads();                   // S4: lgB ready

    if (v == 0 && t >= 1){
      float vv = 0.0f;
      if (lane < 6){
        float gi=lgB[lane],gf=lgB[6+lane],gg=lgB[12+lane],go=lgB[18+lane];
        cB = sigf(gf)*cB + sigf(gi)*tanhf_fast(gg);
        float hv = sigf(go)*tanhf_fast(cB);
        cell_store(ws + WS_BIG + ((pc+1)&3)*3072 + (6*w+lane)*2, hv, (unsigned)(pc+1));
        vv = hv * ow;
      }
      if (lane < 8){
        vv += __shfl_xor(vv,1); vv += __shfl_xor(vv,2); vv += __shfl_xor(vv,4);
        if (lane == 0) g_store(&outp[(size_t)(t-1)*NWG + w], vv);
      }
    }
  }

  // ================= Finalize + reduce =================
  if (v == 0){
    asm volatile("s_waitcnt vmcnt(0)" ::: "memory");   // all outp/cell stores acked
    if (lane == 0) cell_store(ws + WS_FIN + w*2, 0.0f, FINTAG);
    const float* fb = ws + WS_FIN + (4*lane)*2;
    f32x4 F0, F1;
    for(;;){
      asm volatile(
        "global_load_dwordx4 %0, %2, off sc0 sc1\n\t"
        "global_load_dwordx4 %1, %2, off offset:16 sc0 sc1\n\t"
        "s_waitcnt vmcnt(0)"
        : "=&v"(F0), "=&v"(F1) : "v"(fb) : "memory");
      bool ok = (__float_as_uint(F0[1])==FINTAG)&(__float_as_uint(F0[3])==FINTAG)
              & (__float_as_uint(F1[1])==FINTAG)&(__float_as_uint(F1[3])==FINTAG);
      if (__all(ok)) break;
      __builtin_amdgcn_s_sleep(1);
    }
  }
  __syncthreads();
  {
    const int tau = w*16 + (tid >> 4);
    const int s4  = tid & 15;
    float s = 0.f;
#pragma unroll
    for (int j = 0; j < 16; ++j) s += g_load(&outp[(size_t)tau*NWG + s4 + 16*j]);
    s += __shfl_xor(s,8); s += __shfl_xor(s,4); s += __shfl_xor(s,2); s += __shfl_xor(s,1);
    if (s4 == 0) out[tau] = s + ob;
  }
}

extern "C" void kernel_launch(void* const* d_in, const int* in_sizes, int n_in,
                              void* d_out, int out_size, void* d_ws, size_t ws_size,
                              hipStream_t stream){
  (void)in_sizes; (void)n_in; (void)out_size; (void)ws_size;
  const float* x     = (const float*)d_in[0];
  const float* e1Wih = (const float*)d_in[1];
  const float* e1Whh = (const float*)d_in[2];
  const float* e1bih = (const float*)d_in[3];
  const float* e1bhh = (const float*)d_in[4];
  const float* e2Wih = (const float*)d_in[5];
  const float* e2Whh = (const float*)d_in[6];
  const float* e2bih = (const float*)d_in[7];
  const float* e2bhh = (const float*)d_in[8];
  const float* d1Wih = (const float*)d_in[9];
  const float* d1Whh = (const float*)d_in[10];
  const float* d1bih = (const float*)d_in[11];
  const float* d1bhh = (const float*)d_in[12];
  const float* d2Wih = (const float*)d_in[13];
  const float* d2Whh = (const float*)d_in[14];
  const float* d2bih = (const float*)d_in[15];
  const float* d2bhh = (const float*)d_in[16];
  const float* outW  = (const float*)d_in[17];
  const float* outb  = (const float*)d_in[18];
  float* out = (float*)d_out;
  float* ws  = (float*)d_ws;

  hipLaunchKernelGGL(init_ws, dim3(32), dim3(256), 0, stream, ws);

  // Plain launch (NOT cooperative): co-residency follows from grid == #CUs
  // at 1 block/CU (high-VGPR kernel); cooperative launch rejects this config.
  hipLaunchKernelGGL(lstm_ae, dim3(NWG), dim3(NTHR), 0, stream,
                     x,
                     e1Wih, e1Whh, e1bih, e1bhh,
                     e2Wih, e2Whh, e2bih, e2bhh,
                     d1Wih, d1Whh, d1bih, d1bhh,
                     d2Wih, d2Whh, d2bih, d2bhh,
                     outW,  outb,  out,   ws);
}

// Round 15
// 24989.835 us; speedup vs baseline: 1.1951x; 1.1250x over previous
//
#include <hip/hip_runtime.h>
#include <math.h>
#include <stdint.h>

#define SEQ   4096
#define NWG   256
#define NTHR  256
#define FINTAG 0x40000000u

// ws layout in dwords. Cells are 8B {f32 h, u32 tag}.
#define WS_BIG  0                    // big ring  [4][1536] cells
#define WS_SML  12288                // small ring [4][768] cells
#define WS_FIN  18432                // final cells [256]
#define WS_OUTP 18944                // outp [4096][256] f32
#define WS_ZERO WS_OUTP

typedef float f32x4 __attribute__((ext_vector_type(4)));
typedef float f32x2 __attribute__((ext_vector_type(2)));

// fast, saturation-safe activations (v_exp_f32 / v_rcp_f32) — validated R9/R12 (absmax 0.0)
__device__ __forceinline__ float sigf(float x){
  float e = __builtin_amdgcn_exp2f(-1.44269504089f * x);   // exp(-x)
  return __builtin_amdgcn_rcpf(1.0f + e);
}
__device__ __forceinline__ float tanhf_fast(float x){
  float e = __builtin_amdgcn_exp2f(2.88539008178f * x);    // exp(2x)
  return 1.0f - 2.0f * __builtin_amdgcn_rcpf(e + 1.0f);    // +-inf-safe
}

__device__ __forceinline__ float wsum64(float v){
#pragma unroll
  for (int m = 32; m > 0; m >>= 1) v += __shfl_xor(v, m);
  return v;
}

__device__ __forceinline__ float g_load(const float* p){
  return __hip_atomic_load(p, __ATOMIC_RELAXED, __HIP_MEMORY_SCOPE_AGENT);
}
__device__ __forceinline__ void g_store(float* p, float v){
  __hip_atomic_store(p, v, __ATOMIC_RELAXED, __HIP_MEMORY_SCOPE_AGENT);
}
// single 8B atomic store: {h, tag} — data IS the signal (sc1 -> LLC)
__device__ __forceinline__ void cell_store(float* cell, float h, unsigned tag){
  unsigned long long pk = ((unsigned long long)tag << 32) | (unsigned long long)__float_as_uint(h);
  __hip_atomic_store((unsigned long long*)cell, pk, __ATOMIC_RELAXED, __HIP_MEMORY_SCOPE_AGENT);
}

#define DOT4(acc, wv4, hv4) \
  acc += (wv4)[0]*(hv4)[0] + (wv4)[1]*(hv4)[1] + (wv4)[2]*(hv4)[2] + (wv4)[3]*(hv4)[3];

// R8-proven transport: sc1 (LLC-direct) loads of this wave's DISJOINT slice.
#define RETRY_BIG(bbp, tgv)                                                  \
  for(;;){                                                                   \
    asm volatile(                                                            \
      "global_load_dwordx4 %0, %3, off sc0 sc1\n\t"                          \
      "global_load_dwordx4 %1, %3, off offset:1024 sc0 sc1\n\t"              \
      "global_load_dwordx4 %2, %3, off offset:2048 sc0 sc1\n\t"              \
      "s_waitcnt vmcnt(0)"                                                   \
      : "=&v"(B0), "=&v"(B1), "=&v"(B2)                                      \
      : "v"(bbp) : "memory");                                                \
    unsigned tgu = (unsigned)(tgv);                                          \
    bool ok = (__float_as_uint(B0[1])==tgu) & (__float_as_uint(B0[3])==tgu)  \
            & (__float_as_uint(B1[1])==tgu) & (__float_as_uint(B1[3])==tgu)  \
            & (__float_as_uint(B2[1])==tgu) & (__float_as_uint(B2[3])==tgu); \
    if (__all(ok)) break;                                                    \
    __builtin_amdgcn_s_sleep(1);                                             \
  }

#define RETRY_SML(sbp, sb2p, tgv)                                            \
  for(;;){                                                                   \
    asm volatile(                                                            \
      "global_load_dwordx4 %0, %2, off sc0 sc1\n\t"                          \
      "global_load_dwordx2 %1, %3, off sc0 sc1\n\t"                          \
      "s_waitcnt vmcnt(0)"                                                   \
      : "=&v"(S0), "=&v"(S1v)                                                \
      : "v"(sbp), "v"(sb2p) : "memory");                                     \
    unsigned tgu = (unsigned)(tgv);                                          \
    bool ok = (__float_as_uint(S0[1])==tgu) & (__float_as_uint(S0[3])==tgu)  \
            & (__float_as_uint(S1v[1])==tgu);                                \
    if (__all(ok)) break;                                                    \
    __builtin_amdgcn_s_sleep(1);                                             \
  }

__global__ void init_ws(float* ws){
  int i = threadIdx.x + blockIdx.x*blockDim.x;
  for (; i < WS_ZERO; i += blockDim.x*gridDim.x)
    __hip_atomic_store(ws + i, 0.0f, __ATOMIC_RELAXED, __HIP_MEMORY_SCOPE_AGENT);
}

__global__ __launch_bounds__(NTHR, 1) void lstm_ae(
    const float* __restrict__ x,
    const float* __restrict__ e1Wih, const float* __restrict__ e1Whh,
    const float* __restrict__ e1bih, const float* __restrict__ e1bhh,
    const float* __restrict__ e2Wih, const float* __restrict__ e2Whh,
    const float* __restrict__ e2bih, const float* __restrict__ e2bhh,
    const float* __restrict__ d1Wih, const float* __restrict__ d1Whh,
    const float* __restrict__ d1bih, const float* __restrict__ d1bhh,
    const float* __restrict__ d2Wih, const float* __restrict__ d2Whh,
    const float* __restrict__ d2bih, const float* __restrict__ d2bhh,
    const float* __restrict__ outW, const float* __restrict__ outb,
    float* __restrict__ out, float* __restrict__ ws)
{
  const int w    = blockIdx.x;
  const int tid  = threadIdx.x;
  const int lane = tid & 63;
  const int v    = tid >> 6;          // wave 0..3 == gate index

  float* outp = ws + WS_OUTP;

  __shared__ float lx[SEQ];           // 16 KB input
  __shared__ float lhB[2][1536];      // staged big h, double-buffered
  __shared__ float lhS[2][768];       // staged small h, double-buffered
  __shared__ float lgB[24], lgS[12];  // gate pre-activations [gate][unit]

  for (int i = tid; i < SEQ; i += NTHR) lx[i] = x[i];

  // ---- weights: gate-parallel mapping. wave v owns gate v of all units. ----
  // big rows: v*1536 + 6w + r (r=0..5). small rows: v*768 + 3w + r (r=0..2).
  // frag (q,j) multiplies h[256q + 4*lane + j].
  f32x4 wR[6][6];   // e1Whh -> d2Whh      (K=1536)
  f32x4 wA[18];     // e2Wih r*6+q (r<3) -> d2Wih r*3+q (r<6)
  f32x4 wB[9];      // e2Whh r*3+q -> d1Wih (Z) -> d1Whh (D)
  float wihB[6], biasB[6], biasS[3], zw[3], bz[3];

#pragma unroll
  for (int r = 0; r < 6; ++r){
    const int row = v*1536 + 6*w + r;
    const float* p = e1Whh + (size_t)row*1536 + 4*lane;
#pragma unroll
    for (int q = 0; q < 6; ++q) wR[r][q] = *(const f32x4*)(p + 256*q);
    wihB[r]  = e1Wih[row];
    biasB[r] = e1bih[row] + e1bhh[row];
  }
#pragma unroll
  for (int r = 0; r < 3; ++r){
    const int row = v*768 + 3*w + r;
    const float* pi = e2Wih + (size_t)row*1536 + 4*lane;
#pragma unroll
    for (int q = 0; q < 6; ++q) wA[r*6+q] = *(const f32x4*)(pi + 256*q);
    const float* ph = e2Whh + (size_t)row*768 + 4*lane;
#pragma unroll
    for (int q = 0; q < 3; ++q) wB[r*3+q] = *(const f32x4*)(ph + 256*q);
    biasS[r] = e2bih[row] + e2bhh[row];
  }

  float cB = 0.0f, cS = 0.0f;   // wave0 lanes 0-5: big cell state; lanes 8-10: small
  const float ob = outb[0];
  float ow = (v == 0 && lane < 6) ? outW[6*w + lane] : 0.0f;

  __syncthreads();   // lx staged

  // ========== Phase EN: critical = e1 big chain; e2 deferred ==========
  // packet g: big = h1[g] (tag g), small = h2[g-1] (tag g)
  for (int g = 0; g <= SEQ; ++g){
    const int slot = g & 3, buf = g & 1;
    {  // --- early: catch big h1[g] ---
      const float* bb = ws + WS_BIG + slot*3072 + (384*v + 2*lane)*2;
      f32x4 B0,B1,B2;
      RETRY_BIG(bb, g);
      *(f32x2*)&lhB[buf][384*v +       2*lane] = f32x2{B0[0], B0[2]};
      *(f32x2*)&lhB[buf][384*v + 128 + 2*lane] = f32x2{B1[0], B1[2]};
      *(f32x2*)&lhB[buf][384*v + 256 + 2*lane] = f32x2{B2[0], B2[2]};
    }
    __syncthreads();                   // S1: big staged

    if (g < SEQ){                      // e1: gate v of units 0..5
      f32x4 H[6];
#pragma unroll
      for (int q = 0; q < 6; ++q) H[q] = *(const f32x4*)&lhB[buf][256*q + 4*lane];
      float a0=0.f,a1=0.f,a2=0.f,a3=0.f,a4=0.f,a5=0.f;
#pragma unroll
      for (int q = 0; q < 6; ++q){
        DOT4(a0, wR[0][q], H[q]); DOT4(a1, wR[1][q], H[q]); DOT4(a2, wR[2][q], H[q]);
        DOT4(a3, wR[3][q], H[q]); DOT4(a4, wR[4][q], H[q]); DOT4(a5, wR[5][q], H[q]);
      }
      a0=wsum64(a0); a1=wsum64(a1); a2=wsum64(a2);
      a3=wsum64(a3); a4=wsum64(a4); a5=wsum64(a5);
      if (lane == 0){
        float xt = lx[g];
        lgB[v*6+0]=a0+wihB[0]*xt+biasB[0]; lgB[v*6+1]=a1+wihB[1]*xt+biasB[1];
        lgB[v*6+2]=a2+wihB[2]*xt+biasB[2]; lgB[v*6+3]=a3+wihB[3]*xt+biasB[3];
        lgB[v*6+4]=a4+wihB[4]*xt+biasB[4]; lgB[v*6+5]=a5+wihB[5]*xt+biasB[5];
      }
    }
    __syncthreads();                   // S2: lgB ready

    if (v == 0 && g < SEQ && lane < 6){  // store h1[g+1] ASAP — recurrence-critical
      float gi=lgB[lane],gf=lgB[6+lane],gg=lgB[12+lane],go=lgB[18+lane];
      cB = sigf(gf)*cB + sigf(gi)*tanhf_fast(gg);
      cell_store(ws + WS_BIG + ((g+1)&3)*3072 + (6*w+lane)*2,
                 sigf(go)*tanhf_fast(cB), (unsigned)(g+1));
    }

    // --- deferred: catch small h2[g-1], compute e2, store h2[g] ---
    if (g >= 1){
      const float* smlb = ws + WS_SML + slot*1536;
      const float* sb  = smlb + (192*v + 2*lane)*2;
      const float* sb2 = smlb + (192*v + 128 + lane)*2;
      f32x4 S0; f32x2 S1v;
      RETRY_SML(sb, sb2, g);
      *(f32x2*)&lhS[buf][192*v + 2*lane] = f32x2{S0[0], S0[2]};
      lhS[buf][192*v + 128 + lane] = S1v[0];
    }
    __syncthreads();                   // S3: small staged

    if (g >= 1){                       // e2: gate v of units 0..2
      f32x4 H[6], S[3];
#pragma unroll
      for (int q = 0; q < 6; ++q) H[q] = *(const f32x4*)&lhB[buf][256*q + 4*lane];
#pragma unroll
      for (int q = 0; q < 3; ++q) S[q] = *(const f32x4*)&lhS[buf][256*q + 4*lane];
      float b0=0.f,b1=0.f,b2=0.f;
#pragma unroll
      for (int q = 0; q < 6; ++q){
        DOT4(b0, wA[0*6+q], H[q]); DOT4(b1, wA[1*6+q], H[q]); DOT4(b2, wA[2*6+q], H[q]);
      }
#pragma unroll
      for (int q = 0; q < 3; ++q){
        DOT4(b0, wB[0*3+q], S[q]); DOT4(b1, wB[1*3+q], S[q]); DOT4(b2, wB[2*3+q], S[q]);
      }
      b0=wsum64(b0); b1=wsum64(b1); b2=wsum64(b2);
      if (lane == 0){
        lgS[v*3+0]=b0+biasS[0]; lgS[v*3+1]=b1+biasS[1]; lgS[v*3+2]=b2+biasS[2];
      }
    }
    __syncthreads();                   // S4: lgS ready

    // Store small tag g+1 UNCONDITIONALLY (g==0: zero initial state — R11 lesson)
    if (v == 0 && lane >= 8 && lane < 11){
      int u = lane - 8;
      float hv = 0.0f;
      if (g >= 1){
        float gi=lgS[u],gf=lgS[3+u],gg=lgS[6+u],go=lgS[9+u];
        cS = sigf(gf)*cS + sigf(gi)*tanhf_fast(gg);
        hv = sigf(go)*tanhf_fast(cS);
      }
      cell_store(ws + WS_SML + ((g+1)&3)*1536 + (3*w+u)*2, hv, (unsigned)(g+1));
    }
  }

  // ========== Phase Z: zW = d1_Wih @ z + bias (packet SEQ+1 small = z) ==========
  {
#pragma unroll
    for (int r = 0; r < 3; ++r){
      const int row = v*768 + 3*w + r;
      const float* p = d1Wih + (size_t)row*768 + 4*lane;
#pragma unroll
      for (int q = 0; q < 3; ++q) wB[r*3+q] = *(const f32x4*)(p + 256*q);
      bz[r] = d1bih[row] + d1bhh[row];
    }
    const int tg = SEQ+1, slot = tg & 3, buf = tg & 1;
    const float* smlb = ws + WS_SML + slot*1536;
    const float* sb  = smlb + (192*v + 2*lane)*2;
    const float* sb2 = smlb + (192*v + 128 + lane)*2;
    f32x4 S0; f32x2 S1v;
    RETRY_SML(sb, sb2, tg);
    *(f32x2*)&lhS[buf][192*v + 2*lane] = f32x2{S0[0], S0[2]};
    lhS[buf][192*v + 128 + lane] = S1v[0];
    __syncthreads();
    f32x4 S[3];
#pragma unroll
    for (int q = 0; q < 3; ++q) S[q] = *(const f32x4*)&lhS[buf][256*q + 4*lane];
    float z0=0.f,z1=0.f,z2=0.f;
#pragma unroll
    for (int q = 0; q < 3; ++q){
      DOT4(z0, wB[0*3+q], S[q]); DOT4(z1, wB[1*3+q], S[q]); DOT4(z2, wB[2*3+q], S[q]);
    }
    zw[0]=wsum64(z0)+bz[0]; zw[1]=wsum64(z1)+bz[1]; zw[2]=wsum64(z2)+bz[2];
  }

  // ---- D-phase weights ----
#pragma unroll
  for (int r = 0; r < 6; ++r){
    const int row = v*1536 + 6*w + r;
    const float* p = d2Whh + (size_t)row*1536 + 4*lane;
#pragma unroll
    for (int q = 0; q < 6; ++q) wR[r][q] = *(const f32x4*)(p + 256*q);
    const float* pi = d2Wih + (size_t)row*768 + 4*lane;
#pragma unroll
    for (int q = 0; q < 3; ++q) wA[r*3+q] = *(const f32x4*)(pi + 256*q);
    biasB[r] = d2bih[row] + d2bhh[row];
  }
#pragma unroll
  for (int r = 0; r < 3; ++r){
    const int row = v*768 + 3*w + r;
    const float* p = d1Whh + (size_t)row*768 + 4*lane;
#pragma unroll
    for (int q = 0; q < 3; ++q) wB[r*3+q] = *(const f32x4*)(p + 256*q);
  }
  cB = 0.0f; cS = 0.0f;

  // ========== Phase D: critical = d1 small chain; d2 deferred ==========
  // packet pc=SEQ+1+t: small = hd1[t], big = hd2[t-1]
  for (int t = 0; t <= SEQ; ++t){
    const int pc = SEQ+1+t, slot = pc & 3, buf = pc & 1;
    if (t >= 1){  // --- critical: catch small hd1[t] ---
      const float* smlb = ws + WS_SML + slot*1536;
      const float* sb  = smlb + (192*v + 2*lane)*2;
      const float* sb2 = smlb + (192*v + 128 + lane)*2;
      f32x4 S0; f32x2 S1v;
      RETRY_SML(sb, sb2, pc);
      *(f32x2*)&lhS[buf][192*v + 2*lane] = f32x2{S0[0], S0[2]};
      lhS[buf][192*v + 128 + lane] = S1v[0];
    }
    __syncthreads();                   // S1: small staged

    if (t < SEQ){                      // d1: gate v of units 0..2
      f32x4 S[3];
      if (t >= 1){
#pragma unroll
        for (int q = 0; q < 3; ++q) S[q] = *(const f32x4*)&lhS[buf][256*q + 4*lane];
      } else {
#pragma unroll
        for (int q = 0; q < 3; ++q) S[q] = (f32x4)0.0f;
      }
      float b0=0.f,b1=0.f,b2=0.f;
#pragma unroll
      for (int q = 0; q < 3; ++q){
        DOT4(b0, wB[0*3+q], S[q]); DOT4(b1, wB[1*3+q], S[q]); DOT4(b2, wB[2*3+q], S[q]);
      }
      b0=wsum64(b0); b1=wsum64(b1); b2=wsum64(b2);
      if (lane == 0){
        lgS[v*3+0]=b0+zw[0]; lgS[v*3+1]=b1+zw[1]; lgS[v*3+2]=b2+zw[2];
      }
    }
    __syncthreads();                   // S2: lgS ready

    if (v == 0){                       // store hd1[t+1] ASAP — recurrence-critical
      if (t < SEQ && lane >= 8 && lane < 11){
        int u = lane - 8;
        float gi=lgS[u],gf=lgS[3+u],gg=lgS[6+u],go=lgS[9+u];
        cS = sigf(gf)*cS + sigf(gi)*tanhf_fast(gg);
        cell_store(ws + WS_SML + ((pc+1)&3)*1536 + (3*w+u)*2,
                   sigf(go)*tanhf_fast(cS), (unsigned)(pc+1));
      }
      if (t == 0 && lane < 6)          // hd2[0] = 0 (slot holds stale data)
        cell_store(ws + WS_BIG + ((pc+1)&3)*3072 + (6*w+lane)*2, 0.0f, (unsigned)(pc+1));
    }

    // --- deferred: catch big hd2[t-1], compute d2, store hd2[t] + out partial ---
    if (t >= 1){
      const float* bb = ws + WS_BIG + slot*3072 + (384*v + 2*lane)*2;
      f32x4 B0,B1,B2;
      RETRY_BIG(bb, pc);
      *(f32x2*)&lhB[buf][384*v +       2*lane] = f32x2{B0[0], B0[2]};
      *(f32x2*)&lhB[buf][384*v + 128 + 2*lane] = f32x2{B1[0], B1[2]};
      *(f32x2*)&lhB[buf][384*v + 256 + 2*lane] = f32x2{B2[0], B2[2]};
    }
    __syncthreads();                   // S3: big staged

    if (t >= 1){                       // d2: big recurrent (H) + small input (S)
      f32x4 H[6], S[3];
#pragma unroll
      for (int q = 0; q < 6; ++q) H[q] = *(const f32x4*)&lhB[buf][256*q + 4*lane];
#pragma unroll
      for (int q = 0; q < 3; ++q) S[q] = *(const f32x4*)&lhS[buf][256*q + 4*lane];
      float a0=0.f,a1=0.f,a2=0.f,a3=0.f,a4=0.f,a5=0.f;
#pragma unroll
      for (int q = 0; q < 6; ++q){
        DOT4(a0, wR[0][q], H[q]); DOT4(a1, wR[1][q], H[q]); DOT4(a2, wR[2][q], H[q]);
        DOT4(a3, wR[3][q], H[q]); DOT4(a4, wR[4][q], H[q]); DOT4(a5, wR[5][q], H[q]);
      }
#pragma unroll
      for (int q = 0; q < 3; ++q){
        DOT4(a0, wA[0*3+q], S[q]); DOT4(a1, wA[1*3+q], S[q]); DOT4(a2, wA[2*3+q], S[q]);
        DOT4(a3, wA[3*3+q], S[q]); DOT4(a4, wA[4*3+q], S[q]); DOT4(a5, wA[5*3+q], S[q]);
      }
      a0=wsum64(a0); a1=wsum64(a1); a2=wsum64(a2);
      a3=wsum64(a3); a4=wsum64(a4); a5=wsum64(a5);
      if (lane == 0){
        lgB[v*6+0]=a0+biasB[0]; lgB[v*6+1]=a1+biasB[1]; lgB[v*6+2]=a2+biasB[2];
        lgB[v*6+3]=a3+biasB[3]; lgB[v*6+4]=a4+biasB[4]; lgB[v*6+5]=a5+biasB[5];
      }
    }
    __syncthreads();                   // S4: lgB ready

    if (v == 0 && t >= 1){
      float vv = 0.0f;
      if (lane < 6){
        float gi=lgB[lane],gf=lgB[6+lane],gg=lgB[12+lane],go=lgB[18+lane];
        cB = sigf(gf)*cB + sigf(gi)*tanhf_fast(gg);
        float hv = sigf(go)*tanhf_fast(cB);
        cell_store(ws + WS_BIG + ((pc+1)&3)*3072 + (6*w+lane)*2, hv, (unsigned)(pc+1));
        vv = hv * ow;
      }
      if (lane < 8){
        vv += __shfl_xor(vv,1); vv += __shfl_xor(vv,2); vv += __shfl_xor(vv,4);
        if (lane == 0) g_store(&outp[(size_t)(t-1)*NWG + w], vv);
      }
    }
  }

  // ================= Finalize + reduce =================
  if (v == 0){
    asm volatile("s_waitcnt vmcnt(0)" ::: "memory");   // all outp/cell stores acked
    if (lane == 0) cell_store(ws + WS_FIN + w*2, 0.0f, FINTAG);
    const float* fb = ws + WS_FIN + (4*lane)*2;
    f32x4 F0, F1;
    for(;;){
      asm volatile(
        "global_load_dwordx4 %0, %2, off sc0 sc1\n\t"
        "global_load_dwordx4 %1, %2, off offset:16 sc0 sc1\n\t"
        "s_waitcnt vmcnt(0)"
        : "=&v"(F0), "=&v"(F1) : "v"(fb) : "memory");
      bool ok = (__float_as_uint(F0[1])==FINTAG)&(__float_as_uint(F0[3])==FINTAG)
              & (__float_as_uint(F1[1])==FINTAG)&(__float_as_uint(F1[3])==FINTAG);
      if (__all(ok)) break;
      __builtin_amdgcn_s_sleep(1);
    }
  }
  __syncthreads();
  {
    const int tau = w*16 + (tid >> 4);
    const int s4  = tid & 15;
    float s = 0.f;
#pragma unroll
    for (int j = 0; j < 16; ++j) s += g_load(&outp[(size_t)tau*NWG + s4 + 16*j]);
    s += __shfl_xor(s,8); s += __shfl_xor(s,4); s += __shfl_xor(s,2); s += __shfl_xor(s,1);
    if (s4 == 0) out[tau] = s + ob;
  }
}

extern "C" void kernel_launch(void* const* d_in, const int* in_sizes, int n_in,
                              void* d_out, int out_size, void* d_ws, size_t ws_size,
                              hipStream_t stream){
  (void)in_sizes; (void)n_in; (void)out_size; (void)ws_size;
  const float* x     = (const float*)d_in[0];
  const float* e1Wih = (const float*)d_in[1];
  const float* e1Whh = (const float*)d_in[2];
  const float* e1bih = (const float*)d_in[3];
  const float* e1bhh = (const float*)d_in[4];
  const float* e2Wih = (const float*)d_in[5];
  const float* e2Whh = (const float*)d_in[6];
  const float* e2bih = (const float*)d_in[7];
  const float* e2bhh = (const float*)d_in[8];
  const float* d1Wih = (const float*)d_in[9];
  const float* d1Whh = (const float*)d_in[10];
  const float* d1bih = (const float*)d_in[11];
  const float* d1bhh = (const float*)d_in[12];
  const float* d2Wih = (const float*)d_in[13];
  const float* d2Whh = (const float*)d_in[14];
  const float* d2bih = (const float*)d_in[15];
  const float* d2bhh = (const float*)d_in[16];
  const float* outW  = (const float*)d_in[17];
  const float* outb  = (const float*)d_in[18];
  float* out = (float*)d_out;
  float* ws  = (float*)d_ws;

  hipLaunchKernelGGL(init_ws, dim3(32), dim3(256), 0, stream, ws);

  // Plain launch (NOT cooperative): co-residency follows from grid == #CUs
  // at 1 block/CU (high-VGPR kernel); cooperative launch rejects this config.
  hipLaunchKernelGGL(lstm_ae, dim3(NWG), dim3(NTHR), 0, stream,
                     x,
                     e1Wih, e1Whh, e1bih, e1bhh,
                     e2Wih, e2Whh, e2bih, e2bhh,
                     d1Wih, d1Whh, d1bih, d1bhh,
                     d2Wih, d2Whh, d2bih, d2bhh,
                     outW,  outb,  out,   ws);
}